// Round 3
// baseline (24.427 us; speedup 1.0000x reference)
//
#include <hip/hip_runtime.h>
#include <hip/hip_bf16.h>

typedef __attribute__((ext_vector_type(8))) short short8_t;
typedef __attribute__((ext_vector_type(4))) float f32x4;

static __device__ __forceinline__ unsigned short f2bf(float f) {
    unsigned int u = __float_as_uint(f);
    unsigned int r = u + 0x7fffu + ((u >> 16) & 1u);   // RNE (finite inputs)
    return (unsigned short)(r >> 16);
}

// Convert f32 [rows_valid][128] -> bf16 [rows_total][128] (zero-padded), plus f32 row norms.
__global__ __launch_bounds__(256) void prep_kernel(
        const float* __restrict__ src, unsigned short* __restrict__ dst,
        float* __restrict__ sq, int rows_valid, int rows_total) {
    int t = threadIdx.x;
    int row = blockIdx.x * 8 + (t >> 5);
    int lane32 = t & 31;
    if (row >= rows_total) return;
    float4 v = make_float4(0.f, 0.f, 0.f, 0.f);
    if (row < rows_valid)
        v = reinterpret_cast<const float4*>(src + (size_t)row * 128)[lane32];
    ushort4 b;
    b.x = f2bf(v.x); b.y = f2bf(v.y); b.z = f2bf(v.z); b.w = f2bf(v.w);
    reinterpret_cast<ushort4*>(dst + (size_t)row * 128)[lane32] = b;
    float s = v.x*v.x + v.y*v.y + v.z*v.z + v.w*v.w;
    #pragma unroll
    for (int m = 16; m >= 1; m >>= 1) s += __shfl_xor(s, m, 64);
    if (lane32 == 0) sq[row] = s;
}

#define LDT 136   // padded LDS row (bf16 elems): 272 B stride -> 4-bank stride, ~2-way (free)

// Each block owns a 32-row output slab [slab0, slab0+32) x [0,1000).
// Loops over 8 column tiles of 128 classes with double-buffered bf16 B tiles.
__global__ __launch_bounds__(512) void main_kernel(
        const float* __restrict__ X,             // [8192][128] f32
        const unsigned short* __restrict__ Bw,   // [1024][128] bf16 bits (padded)
        const float* __restrict__ psq,           // [1024] f32
        float* __restrict__ out) {               // [8192][1000] f32
    __shared__ unsigned short As[32][LDT];
    __shared__ unsigned short Bs[2][128][LDT];
    __shared__ float xq_s[32];
    __shared__ float trans[8][16][16];           // wave-private transpose scratch

    const int t = threadIdx.x;
    const int slab0 = blockIdx.x * 32;

    // ---- stage A: 32 rows x 128 f32 -> bf16 LDS, + row norms (once) ----
    {
        int r = t >> 4;               // 16 threads per row
        int c8 = (t & 15) * 8;
        const float4* src = reinterpret_cast<const float4*>(X + (size_t)(slab0 + r) * 128 + c8);
        float4 v0 = src[0], v1 = src[1];
        short8_t b;
        b[0] = (short)f2bf(v0.x); b[1] = (short)f2bf(v0.y);
        b[2] = (short)f2bf(v0.z); b[3] = (short)f2bf(v0.w);
        b[4] = (short)f2bf(v1.x); b[5] = (short)f2bf(v1.y);
        b[6] = (short)f2bf(v1.z); b[7] = (short)f2bf(v1.w);
        *reinterpret_cast<short8_t*>(&As[r][c8]) = b;
        float s = v0.x*v0.x + v0.y*v0.y + v0.z*v0.z + v0.w*v0.w
                + v1.x*v1.x + v1.y*v1.y + v1.z*v1.z + v1.w*v1.w;
        s += __shfl_xor(s, 1, 64);
        s += __shfl_xor(s, 2, 64);
        s += __shfl_xor(s, 4, 64);
        s += __shfl_xor(s, 8, 64);
        if ((t & 15) == 0) xq_s[r] = s;
    }
    // ---- stage B tile 0 directly ----
    {
        int r = t >> 2;               // 0..127
        int cb = (t & 3) * 32;
        const unsigned short* src = Bw + (size_t)r * 128 + cb;
        #pragma unroll
        for (int k = 0; k < 4; ++k) {
            short8_t v = *reinterpret_cast<const short8_t*>(src + k * 8);
            *reinterpret_cast<short8_t*>(&Bs[0][r][cb + k * 8]) = v;
        }
    }
    __syncthreads();

    const int wave = t >> 6;
    const int lane = t & 63;
    const int wm  = (wave >> 2) * 16;    // A-row group: 0 / 16
    const int wcb = (wave & 3) * 32;     // B-col group: 0/32/64/96
    const int lr  = lane & 15;
    const int lkb = (lane >> 4) * 8;

    // Hoist A fragments (A tile never changes).
    short8_t afrag[4];
    #pragma unroll
    for (int ks = 0; ks < 4; ++ks)
        afrag[ks] = *reinterpret_cast<const short8_t*>(&As[wm + lr][ks * 32 + lkb]);
    const float4 xq4 = *reinterpret_cast<const float4*>(&xq_s[wm + (lane >> 4) * 4]);

    const int rr = lane >> 2;            // transpose-read row 0..15
    const int cq = (lane & 3) * 4;       // transpose-read col quad
    const int rbase = (lane >> 4) * 4;   // acc row base (C/D layout, m89)

    int cur = 0;
    #pragma unroll 1
    for (int cn = 0; cn < 8; ++cn) {
        // Prefetch next B tile to registers (latency hides under compute).
        short8_t pf[4];
        if (cn < 7) {
            int r = t >> 2;
            int cb = (t & 3) * 32;
            const unsigned short* src = Bw + (size_t)((cn + 1) * 128 + r) * 128 + cb;
            #pragma unroll
            for (int k = 0; k < 4; ++k)
                pf[k] = *reinterpret_cast<const short8_t*>(src + k * 8);
        }
        // Compute two 16x16 subtiles on Bs[cur].
        #pragma unroll
        for (int ni = 0; ni < 2; ++ni) {
            f32x4 acc = {0.f, 0.f, 0.f, 0.f};
            #pragma unroll
            for (int ks = 0; ks < 4; ++ks) {
                short8_t bfrag = *reinterpret_cast<const short8_t*>(
                        &Bs[cur][wcb + ni * 16 + lr][ks * 32 + lkb]);
                acc = __builtin_amdgcn_mfma_f32_16x16x32_bf16(afrag[ks], bfrag, acc, 0, 0, 0);
            }
            // Epilogue: 2*acc - xsq (lane-local), transpose in wave-private LDS,
            // then aligned float4 store of full row segments.
            #pragma unroll
            for (int j = 0; j < 4; ++j)
                trans[wave][rbase + j][lr] = 2.f * acc[j] - ((const float*)&xq4)[j];
            float4 tv = *reinterpret_cast<const float4*>(&trans[wave][rr][cq]);
            int col = cn * 128 + wcb + ni * 16 + cq;
            if (col < 1000) {
                float4 pq = *reinterpret_cast<const float4*>(psq + col);
                tv.x -= pq.x; tv.y -= pq.y; tv.z -= pq.z; tv.w -= pq.w;
                *reinterpret_cast<float4*>(out + (size_t)(slab0 + wm + rr) * 1000 + col) = tv;
            }
        }
        // Write prefetched tile into the other buffer; one barrier per iter.
        if (cn < 7) {
            int r = t >> 2;
            int cb = (t & 3) * 32;
            #pragma unroll
            for (int k = 0; k < 4; ++k)
                *reinterpret_cast<short8_t*>(&Bs[cur ^ 1][r][cb + k * 8]) = pf[k];
            __syncthreads();
            cur ^= 1;
        }
    }
}

// Correct-but-slow fallback if workspace is too small.
__global__ __launch_bounds__(256) void naive_kernel(
        const float* __restrict__ x, const float* __restrict__ p,
        float* __restrict__ out) {
    long long idx = (long long)blockIdx.x * 256 + threadIdx.x;
    if (idx >= (long long)8192 * 1000) return;
    int n = (int)(idx / 1000);
    int c = (int)(idx % 1000);
    const float4* xr = reinterpret_cast<const float4*>(x + (size_t)n * 128);
    const float4* pr = reinterpret_cast<const float4*>(p + (size_t)c * 128);
    float d = 0.f;
    #pragma unroll
    for (int i = 0; i < 32; ++i) {
        float4 a = xr[i], b = pr[i];
        float dx = a.x - b.x, dy = a.y - b.y, dz = a.z - b.z, dw = a.w - b.w;
        d += dx * dx + dy * dy + dz * dz + dw * dw;
    }
    out[idx] = -d;
}

extern "C" void kernel_launch(void* const* d_in, const int* in_sizes, int n_in,
                              void* d_out, int out_size, void* d_ws, size_t ws_size,
                              hipStream_t stream) {
    const float* x = (const float*)d_in[0];   // (8192, 128) f32
    const float* p = (const float*)d_in[1];   // (1000, 128) f32
    float* out = (float*)d_out;               // (8192, 1000) f32

    const size_t pb_elems = (size_t)1024 * 128;
    const size_t need = pb_elems * 2 + 1024 * 4;

    if (ws_size >= need) {
        unsigned short* pb = (unsigned short*)d_ws;
        float* psq = (float*)(pb + pb_elems);
        prep_kernel<<<128, 256, 0, stream>>>(p, pb, psq, 1000, 1024);
        main_kernel<<<256, 512, 0, stream>>>(x, pb, psq, out);
    } else {
        naive_kernel<<<((size_t)8192 * 1000 + 255) / 256, 256, 0, stream>>>(x, p, out);
    }
}